// Round 19
// baseline (4883.722 us; speedup 1.0000x reference)
//
#include <hip/hip_runtime.h>
#include <stdint.h>

namespace {

constexpr int B_   = 512;
constexpr int T_   = 512;
constexpr int IN_  = 6;
constexpr int H_   = 64;
constexpr int HH_  = 128;
constexpr int OUT_ = 8;
constexpr int ME   = 16;          // batch elements per block (MFMA M)
constexpr int PPR  = 103;         // pp row stride in f32 (odd -> banks spread)

typedef _Float16 f16x8 __attribute__((ext_vector_type(8)));
typedef float    f32x4 __attribute__((ext_vector_type(4)));

__device__ __forceinline__ f32x4 mfma16(f16x8 a, f16x8 b, f32x4 c) {
    return __builtin_amdgcn_mfma_f32_16x16x32_f16(a, b, c, 0, 0, 0);
}

// B-fragment: lane supplies B[k0 + (lane>>4)*8 + s][n0 + (lane&15)], s=0..7
// (verified end-to-end R17/R18: absmax 7.8e-3 with real weights)
__device__ __forceinline__ f16x8 loadB(const float* __restrict__ W, int N,
                                       int k0, int n0, int lane) {
    f16x8 r;
    const int kb = k0 + ((lane >> 4) << 3);
    const int n  = n0 + (lane & 15);
    #pragma unroll
    for (int s = 0; s < 8; ++s) r[s] = (_Float16)W[(kb + s) * N + n];
    return r;
}

// A-fragment from LDS act buffer (chunk = k>>3; u32[chunk*64 + m*4 .. +3])
__device__ __forceinline__ f16x8 loadA(const uint32_t* __restrict__ buf, int ks, int lane) {
    uint4 q = *reinterpret_cast<const uint4*>(
        buf + (((ks >> 3) + (lane >> 4)) << 6) + ((lane & 15) << 2));
    return __builtin_bit_cast(f16x8, q);
}

__device__ __forceinline__ uint32_t packh2(float a, float b) {
    union { _Float16 h[2]; uint32_t u; } p;
    p.h[0] = (_Float16)a;
    p.h[1] = (_Float16)b;
    return p.u;
}

__device__ __forceinline__ float tanh_fast(float v) {
    float ax = fabsf(v);
    float e  = __expf(2.0f * ax);
    float r  = 1.0f - 2.0f / (e + 1.0f);
    return copysignf(r, v);
}

// One workgroup (256 threads, 4 waves) per 16 batch elements; grid 32
// (1 block/CU, 1 wave/SIMD). 4 barrier-phases per vf eval, 4-wave barriers
// (vs R18's 8-wave: less skew). ALL B-fragments in registers (176 u32 —
// allowed at 1 wave/SIMD by the mirror law: VGPR<=256).
// Waves: G1/G2/G3 n-slice [32w,32w+32) (2 tiles); G4 [96w,96w+96) (6 tiles)
// = A-rows [16w,16w+16) -> einsum/RK4/h wave-local. Lane owns element
// e=lane&15, rows r=16w+4*(lane>>4)+p (p=0..3); dX in 6 regs per lane.
__global__ __launch_bounds__(256, 1) void cde_kernel(
    const float* __restrict__ x,
    const float* __restrict__ W_init, const float* __restrict__ b_init,
    const float* __restrict__ W_in,   const float* __restrict__ b_in,
    const float* __restrict__ W_h1,   const float* __restrict__ b_h1,
    const float* __restrict__ W_h2,   const float* __restrict__ b_h2,
    const float* __restrict__ W_out,  const float* __restrict__ b_out,
    const float* __restrict__ W_fin,  const float* __restrict__ b_fin,
    float* __restrict__ out)
{
    const int t    = threadIdx.x;
    const int lane = t & 63;
    const int w    = t >> 6;               // wave 0..3
    const int le   = lane & 15;            // element slot
    const int g    = lane >> 4;            // row-group 0..3
    const int b0   = blockIdx.x * ME;

    __shared__ alignas(16) uint32_t bufA[16 * 64];      // h / z2, 4KB
    __shared__ alignas(16) uint32_t bufB[16 * 64];      // z1 / z3, 4KB
    __shared__ float pw[4][16 * PPR];                   // per-wave tanh scratch
    __shared__ float dxs[2][ME * IN_];                  // step-parity dbuf

    // ---- B-fragments, all register-resident ----
    f16x8 b1[4], b2[8], b3[8], b4[24];
    #pragma unroll
    for (int tt = 0; tt < 2; ++tt)
        #pragma unroll
        for (int ks = 0; ks < 2; ++ks)
            b1[tt * 2 + ks] = loadB(W_in, HH_, ks * 32, 32 * w + 16 * tt, lane);
    #pragma unroll
    for (int tt = 0; tt < 2; ++tt)
        #pragma unroll
        for (int ks = 0; ks < 4; ++ks) {
            b2[tt * 4 + ks] = loadB(W_h1, HH_, ks * 32, 32 * w + 16 * tt, lane);
            b3[tt * 4 + ks] = loadB(W_h2, HH_, ks * 32, 32 * w + 16 * tt, lane);
        }
    #pragma unroll
    for (int tt = 0; tt < 6; ++tt)
        #pragma unroll
        for (int ks = 0; ks < 4; ++ks)
            b4[tt * 4 + ks] = loadB(W_out, 384, ks * 32, 96 * w + 16 * tt, lane);

    float binw[2], bh1w[2], bh2w[2], bow[6];
    #pragma unroll
    for (int tt = 0; tt < 2; ++tt) {
        binw[tt] = b_in[32 * w + 16 * tt + le];
        bh1w[tt] = b_h1[32 * w + 16 * tt + le];
        bh2w[tt] = b_h2[32 * w + 16 * tt + le];
    }
    #pragma unroll
    for (int tt = 0; tt < 6; ++tt) bow[tt] = b_out[96 * w + 16 * tt + le];

    // W_fin B-frags + b_fin (wave 0; out-cols 8..15 zero-padded)
    f16x8 wf0, wf1;
    float bfin_r = 0.f;
    #pragma unroll
    for (int s = 0; s < 8; ++s) { wf0[s] = (_Float16)0.f; wf1[s] = (_Float16)0.f; }
    if (w == 0) {
        #pragma unroll
        for (int s = 0; s < 8; ++s) {
            wf0[s] = (le < 8) ? (_Float16)W_fin[(g * 8 + s) * OUT_ + le] : (_Float16)0.f;
            wf1[s] = (le < 8) ? (_Float16)W_fin[(32 + g * 8 + s) * OUT_ + le] : (_Float16)0.f;
        }
        bfin_r = (le < 8) ? b_fin[le] : 0.f;
    }

    // dX producers: threads 0..95 (e = t/6, i = t%6)
    float  xa = 0.f, xb = 0.f;
    size_t xdb = 0;
    if (t < 96) {
        int e = t / 6, i = t - 6 * (t / 6);
        xdb = ((size_t)(b0 + e) * T_) * IN_ + i;
        xa = x[xdb];
        xb = x[xdb + IN_];
        dxs[0][t] = xb - xa;               // dX for step 0
        xa = xb;
        xb = x[xdb + 2 * IN_];
    }

    // ---- h0: lane owns (e=le, r=16w+4g+p), p=0..3 ----
    float h_reg[4], hacc[4] = {0.f, 0.f, 0.f, 0.f};
    {
        const float* xe = x + (size_t)(b0 + le) * T_ * IN_;
        float xr[IN_];
        #pragma unroll
        for (int i = 0; i < IN_; ++i) xr[i] = xe[i];
        #pragma unroll
        for (int p = 0; p < 4; ++p) {
            int r = 16 * w + 4 * g + p;
            float s = b_init[r];
            #pragma unroll
            for (int i = 0; i < IN_; ++i) s += xr[i] * W_init[i * H_ + r];
            h_reg[p] = s;
        }
        const int chunk = 2 * w + (g >> 1);
        bufA[chunk * 64 + le * 4 + ((2 * g) & 3)]     = packh2(h_reg[0], h_reg[1]);
        bufA[chunk * 64 + le * 4 + ((2 * g + 1) & 3)] = packh2(h_reg[2], h_reg[3]);
    }
    __syncthreads();

#define OUT_MFMA(TT)                                                           \
    {                                                                          \
        f32x4 oc = {0.f, 0.f, 0.f, 0.f};                                       \
        oc = mfma16(loadA(bufA, 0, lane),  wf0, oc);                           \
        oc = mfma16(loadA(bufA, 32, lane), wf1, oc);                           \
        if (le < 8) {                                                          \
            _Pragma("unroll")                                                  \
            for (int j = 0; j < 4; ++j) {                                      \
                int m = g * 4 + j;                                             \
                out[((size_t)(b0 + m) * T_ + (TT)) * OUT_ + le] = oc[j] + bfin_r; \
            }                                                                  \
        }                                                                      \
    }

    float dxr[IN_];

    for (int step = 0; step < T_ - 1; ++step) {
        const float* dxc = dxs[step & 1];
        float*       dxn = dxs[(step + 1) & 1];
        #pragma unroll
        for (int s4 = 0; s4 < 4; ++s4) {
            // ---- ph1: G1 h -> z1 into bufB (+ dxr load / OUT on s4==0) ----
            if (s4 == 0) {
                #pragma unroll
                for (int i = 0; i < IN_; ++i) dxr[i] = dxc[le * 6 + i];
                if (w == 0) { OUT_MFMA(step) }
            }
            {
                f16x8 ha0 = loadA(bufA, 0, lane);
                f16x8 ha1 = loadA(bufA, 32, lane);
                f32x4 c0 = {0.f, 0.f, 0.f, 0.f};
                f32x4 c1 = {0.f, 0.f, 0.f, 0.f};
                c0 = mfma16(ha0, b1[0], c0); c0 = mfma16(ha1, b1[1], c0);
                c1 = mfma16(ha0, b1[2], c1); c1 = mfma16(ha1, b1[3], c1);
                _Float16* zb = (_Float16*)bufB;
                #pragma unroll
                for (int tt = 0; tt < 2; ++tt) {
                    int n = 32 * w + 16 * tt + le;
                    int base = (n >> 3) * 128 + (n & 7);
                    #pragma unroll
                    for (int j = 0; j < 4; ++j) {
                        float v = (tt ? c1[j] : c0[j]) + binw[tt];
                        zb[base + (4 * g + j) * 8] = (_Float16)fmaxf(v, 0.f);
                    }
                }
            }
            __syncthreads();

            // ---- ph2: G2 z1 -> z2 into bufA ----
            {
                f16x8 a0 = loadA(bufB, 0, lane);
                f16x8 a1 = loadA(bufB, 32, lane);
                f16x8 a2 = loadA(bufB, 64, lane);
                f16x8 a3 = loadA(bufB, 96, lane);
                _Float16* zb = (_Float16*)bufA;
                #pragma unroll
                for (int tt = 0; tt < 2; ++tt) {
                    f32x4 u = {0.f, 0.f, 0.f, 0.f};
                    f32x4 v = {0.f, 0.f, 0.f, 0.f};
                    u = mfma16(a0, b2[tt * 4 + 0], u); v = mfma16(a1, b2[tt * 4 + 1], v);
                    u = mfma16(a2, b2[tt * 4 + 2], u); v = mfma16(a3, b2[tt * 4 + 3], v);
                    int n = 32 * w + 16 * tt + le;
                    int base = (n >> 3) * 128 + (n & 7);
                    #pragma unroll
                    for (int j = 0; j < 4; ++j)
                        zb[base + (4 * g + j) * 8] = (_Float16)fmaxf(u[j] + v[j] + bh1w[tt], 0.f);
                }
            }
            __syncthreads();

            // ---- ph3: G3 z2 -> z3 into bufB ----
            {
                f16x8 a0 = loadA(bufA, 0, lane);
                f16x8 a1 = loadA(bufA, 32, lane);
                f16x8 a2 = loadA(bufA, 64, lane);
                f16x8 a3 = loadA(bufA, 96, lane);
                _Float16* zb = (_Float16*)bufB;
                #pragma unroll
                for (int tt = 0; tt < 2; ++tt) {
                    f32x4 u = {0.f, 0.f, 0.f, 0.f};
                    f32x4 v = {0.f, 0.f, 0.f, 0.f};
                    u = mfma16(a0, b3[tt * 4 + 0], u); v = mfma16(a1, b3[tt * 4 + 1], v);
                    u = mfma16(a2, b3[tt * 4 + 2], u); v = mfma16(a3, b3[tt * 4 + 3], v);
                    int n = 32 * w + 16 * tt + le;
                    int base = (n >> 3) * 128 + (n & 7);
                    #pragma unroll
                    for (int j = 0; j < 4; ++j)
                        zb[base + (4 * g + j) * 8] = (_Float16)fmaxf(u[j] + v[j] + bh2w[tt], 0.f);
                }
            }
            __syncthreads();

            // ---- ph4: G4 (6 tiles) + wave-local einsum + RK4 + h-write ----
            {
                f16x8 v0 = loadA(bufB, 0, lane);
                f16x8 v1 = loadA(bufB, 32, lane);
                f16x8 v2 = loadA(bufB, 64, lane);
                f16x8 v3 = loadA(bufB, 96, lane);
                float* pwl = pw[w];
                #pragma unroll
                for (int tt = 0; tt < 6; ++tt) {
                    f32x4 u  = {0.f, 0.f, 0.f, 0.f};
                    f32x4 vv = {0.f, 0.f, 0.f, 0.f};
                    u  = mfma16(v0, b4[tt * 4 + 0], u);
                    vv = mfma16(v1, b4[tt * 4 + 1], vv);
                    u  = mfma16(v2, b4[tt * 4 + 2], u);
                    vv = mfma16(v3, b4[tt * 4 + 3], vv);
                    #pragma unroll
                    for (int j = 0; j < 4; ++j)
                        pwl[(4 * g + j) * PPR + 16 * tt + le] =
                            tanh_fast(u[j] + vv[j] + bow[tt]);
                }
                // kv (dx applied at read; e=le is lane-local) + RK4
                float hs[4];
                #pragma unroll
                for (int p = 0; p < 4; ++p) {
                    const float* pr = &pwl[le * PPR + (4 * g + p) * 6];
                    float kv = pr[0] * dxr[0] + pr[1] * dxr[1] + pr[2] * dxr[2]
                             + pr[3] * dxr[3] + pr[4] * dxr[4] + pr[5] * dxr[5];
                    hacc[p] += ((s4 == 1 || s4 == 2) ? 2.0f : 1.0f) * kv;
                    if (s4 < 3) {
                        hs[p] = h_reg[p] + ((s4 == 2) ? 1.0f : 0.5f) * kv;
                    } else {
                        h_reg[p] += hacc[p] * (1.0f / 6.0f);
                        hacc[p] = 0.f;
                        hs[p] = h_reg[p];
                    }
                }
                const int chunk = 2 * w + (g >> 1);
                bufA[chunk * 64 + le * 4 + ((2 * g) & 3)]     = packh2(hs[0], hs[1]);
                bufA[chunk * 64 + le * 4 + ((2 * g + 1) & 3)] = packh2(hs[2], hs[3]);
                // dX for step+1 (parity buffer)
                if (s4 == 3 && t < 96) {
                    dxn[t] = xb - xa;
                    xa = xb;
                    if (step + 3 < T_) xb = x[xdb + (size_t)(step + 3) * IN_];
                }
            }
            __syncthreads();
        }
    }

    if (w == 0) { OUT_MFMA(T_ - 1) }
#undef OUT_MFMA
}

} // namespace

extern "C" void kernel_launch(void* const* d_in, const int* in_sizes, int n_in,
                              void* d_out, int out_size, void* d_ws, size_t ws_size,
                              hipStream_t stream) {
    const float* x      = (const float*)d_in[0];
    const float* W_init = (const float*)d_in[1];
    const float* b_init = (const float*)d_in[2];
    const float* W_in   = (const float*)d_in[3];
    const float* b_in   = (const float*)d_in[4];
    const float* W_h1   = (const float*)d_in[5];
    const float* b_h1   = (const float*)d_in[6];
    const float* W_h2   = (const float*)d_in[7];
    const float* b_h2   = (const float*)d_in[8];
    const float* W_out  = (const float*)d_in[9];
    const float* b_out  = (const float*)d_in[10];
    const float* W_fin  = (const float*)d_in[11];
    const float* b_fin  = (const float*)d_in[12];
    float* out = (float*)d_out;

    cde_kernel<<<dim3(B_ / ME), dim3(256), 0, stream>>>(
        x, W_init, b_init, W_in, b_in, W_h1, b_h1, W_h2, b_h2,
        W_out, b_out, W_fin, b_fin, out);
}

// Round 20
// 3250.417 us; speedup vs baseline: 1.5025x; 1.5025x over previous
//
#include <hip/hip_runtime.h>
#include <stdint.h>

namespace {

constexpr int B_   = 512;
constexpr int T_   = 512;
constexpr int IN_  = 6;
constexpr int H_   = 64;
constexpr int HH_  = 128;
constexpr int OUT_ = 8;

typedef _Float16 f16x2 __attribute__((ext_vector_type(2)));

__device__ __forceinline__ float dot2f(uint32_t w, uint32_t z, float acc) {
    return __builtin_amdgcn_fdot2(__builtin_bit_cast(f16x2, w),
                                  __builtin_bit_cast(f16x2, z), acc, false);
}

__device__ __forceinline__ uint32_t pack2f(float a, float b) {
    f16x2 p;
    p[0] = (_Float16)a;
    p[1] = (_Float16)b;
    return __builtin_bit_cast(uint32_t, p);
}

// pair sum across kh lanes (t ^ 1) via DPP quad_perm [1,0,3,2] — pure VALU.
__device__ __forceinline__ float pxor1(float v) {
    int y = __builtin_amdgcn_mov_dpp(__builtin_bit_cast(int, v), 0xB1, 0xF, 0xF, true);
    return v + __builtin_bit_cast(float, y);
}
// pair sum across c-parity lanes (t ^ 2) via DPP quad_perm [2,3,0,1].
__device__ __forceinline__ float pxor2(float v) {
    int y = __builtin_amdgcn_mov_dpp(__builtin_bit_cast(int, v), 0x4E, 0xF, 0xF, true);
    return v + __builtin_bit_cast(float, y);
}

__device__ __forceinline__ float tanh_fast(float v) {
    float ax = fabsf(v);
    float e  = __expf(2.0f * ax);
    float r  = 1.0f - 2.0f / (e + 1.0f);
    return copysignf(r, v);
}

// Session champion (R11, 3228 us). One workgroup (256 threads) per batch
// element, grid 512 -> 2 independently-barriered blocks co-resident per CU
// (mirror law: VGPR<=128) — the interleave that defines the measured
// latency-structural plateau: 2044 evals x 4 barrier-phases x ~950 cyc.
// Thread t: z-col c = t>>1, k-half kh = t&1. w2,w3,w4 in regs (spill ~80 u32
// is off the critical path — removing it in R15/R16 did not move the wall);
// W_in in LDS [kp][c]; in-register einsum; DPP reductions.
__global__ __launch_bounds__(256, 2) void cde_kernel(
    const float* __restrict__ x,
    const float* __restrict__ W_init, const float* __restrict__ b_init,
    const float* __restrict__ W_in,   const float* __restrict__ b_in,
    const float* __restrict__ W_h1,   const float* __restrict__ b_h1,
    const float* __restrict__ W_h2,   const float* __restrict__ b_h2,
    const float* __restrict__ W_out,  const float* __restrict__ b_out,
    const float* __restrict__ W_fin,  const float* __restrict__ b_fin,
    float* __restrict__ out)
{
    const int t  = threadIdx.x;
    const int c  = t >> 1;      // 0..127 (z-column)
    const int kh = t & 1;       // k-half
    const int b  = blockIdx.x;

    __shared__ alignas(16) uint32_t hinu[H_ / 2];    // h as f16 pairs
    __shared__ alignas(16) uint32_t zAu[HH_ / 2];    // activation ping
    __shared__ alignas(16) uint32_t zBu[HH_ / 2];    // activation pong
    __shared__ uint32_t w1s[32 * HH_];               // W_in packed [kp][c], 16KB
    __shared__ float dxs[IN_];
    __shared__ float hbuf[H_];
    __shared__ float wfin_s[H_ * OUT_];
    __shared__ float bfin_s[OUT_];

    // ---- register-resident f16 weights (k-half slice): 32+32+96 = 160 u32 ----
    uint32_t w2[32], w3[32], w4[96];
    #pragma unroll
    for (int i = 0; i < 32; ++i) {
        int k = kh * 64 + 2 * i;
        w2[i] = pack2f(W_h1[k * HH_ + c], W_h1[(k + 1) * HH_ + c]);
        w3[i] = pack2f(W_h2[k * HH_ + c], W_h2[(k + 1) * HH_ + c]);
    }
    #pragma unroll
    for (int j = 0; j < 3; ++j) {
        const int col = 3 * c + j;
        #pragma unroll
        for (int i = 0; i < 32; ++i) {
            int k = kh * 64 + 2 * i;
            w4[j * 32 + i] = pack2f(W_out[k * 384 + col], W_out[(k + 1) * 384 + col]);
        }
    }
    // W_in -> LDS, packed k-pairs, layout [kp][c] (reads: 2-lane broadcast)
    for (int i = t; i < 32 * HH_; i += 256) {
        int kp = i >> 7, cc = i & 127;
        w1s[i] = pack2f(W_in[(2 * kp) * HH_ + cc], W_in[(2 * kp + 1) * HH_ + cc]);
    }
    for (int i = t; i < H_ * OUT_; i += 256) wfin_s[i] = W_fin[i];
    if (t < OUT_) bfin_s[t] = b_fin[t];

    const float bin_r = b_in[c];
    const float bh1_r = b_h1[c];
    const float bh2_r = b_h2[c];
    float bo[3];
    #pragma unroll
    for (int j = 0; j < 3; ++j) bo[j] = b_out[3 * c + j];
    const int  dbase = (c & 1) * 3;   // dX dims of this thread's 3 A-cols
    const int  r_own = t >> 2;        // A/h row this quad owns
    const bool wrt   = (t & 3) == 0;  // state writer lanes (64 = 64 rows)

    const size_t xbase = (size_t)b * T_ * IN_;
    const size_t obase = (size_t)b * T_ * OUT_;

    // dX producer: threads 0..5
    float xa = 0.f, xb = 0.f;
    if (t < IN_) {
        xa = x[xbase + t];
        xb = x[xbase + IN_ + t];
        dxs[t] = xb - xa;                 // dX for step 0
        xa = xb;
        xb = x[xbase + 2 * IN_ + t];
    }

    // ---- h0 (threads t<64) ----
    if (t < H_) {
        float s = b_init[t];
        #pragma unroll
        for (int i = 0; i < IN_; ++i) s += x[xbase + i] * W_init[i * H_ + t];
        hbuf[t] = s;
        ((_Float16*)hinu)[t] = (_Float16)s;
    }
    __syncthreads();

    // RK4 state (maintained redundantly in the 4 lanes of each row quad)
    float h_reg = hbuf[r_own];
    float hacc  = 0.f;

#define OUT_STAGE(TT)                                                          \
    if (t < 64) {                                                              \
        int o_ = t & 7, part_ = t >> 3;                                        \
        float s_ = 0.f;                                                        \
        _Pragma("unroll")                                                      \
        for (int j = 0; j < 8; ++j)                                            \
            s_ += hbuf[part_ * 8 + j] * wfin_s[(part_ * 8 + j) * OUT_ + o_];   \
        s_ += __shfl_xor(s_, 8);                                               \
        s_ += __shfl_xor(s_, 16);                                              \
        s_ += __shfl_xor(s_, 32);                                              \
        if (part_ == 0)                                                        \
            out[obase + (size_t)(TT) * OUT_ + o_] = s_ + bfin_s[o_];           \
    }

    OUT_STAGE(0)

    float dxr[3];

    for (int step = 0; step < T_ - 1; ++step) {
        #pragma unroll
        for (int s4 = 0; s4 < 4; ++s4) {
            // ---- phase 1: (dxr reload + out-stage on s4==0) + G1: h -> z1 ----
            if (s4 == 0) {
                #pragma unroll
                for (int j = 0; j < 3; ++j) dxr[j] = dxs[dbase + j];
                if (step > 0) { OUT_STAGE(step) }
            }
            {
                uint32_t hv[16];
                const uint32_t* hp = hinu + kh * 16;
                *(uint4*)&hv[0]  = *(const uint4*)(hp);
                *(uint4*)&hv[4]  = *(const uint4*)(hp + 4);
                *(uint4*)&hv[8]  = *(const uint4*)(hp + 8);
                *(uint4*)&hv[12] = *(const uint4*)(hp + 12);
                const int w1base = (kh * 16) * HH_ + c;
                float a0 = 0.f, a1 = 0.f, a2 = 0.f, a3 = 0.f;
                #pragma unroll
                for (int i = 0; i < 16; ++i) {
                    uint32_t wv = w1s[w1base + i * HH_];
                    if ((i & 3) == 0)      a0 = dot2f(wv, hv[i], a0);
                    else if ((i & 3) == 1) a1 = dot2f(wv, hv[i], a1);
                    else if ((i & 3) == 2) a2 = dot2f(wv, hv[i], a2);
                    else                   a3 = dot2f(wv, hv[i], a3);
                }
                float z = fmaxf(bin_r + pxor1((a0 + a1) + (a2 + a3)), 0.f);
                if (kh == 0) ((_Float16*)zAu)[c] = (_Float16)z;
            }
            __syncthreads();

            // ---- phase 2: G2 zA -> zB ----
            {
                uint32_t zv[32];
                const uint32_t* zp = zAu + kh * 32;
                #pragma unroll
                for (int q = 0; q < 8; ++q)
                    *(uint4*)&zv[4 * q] = *(const uint4*)(zp + 4 * q);
                float a0 = 0.f, a1 = 0.f, a2 = 0.f, a3 = 0.f;
                #pragma unroll
                for (int i = 0; i < 32; ++i) {
                    if ((i & 3) == 0)      a0 = dot2f(w2[i], zv[i], a0);
                    else if ((i & 3) == 1) a1 = dot2f(w2[i], zv[i], a1);
                    else if ((i & 3) == 2) a2 = dot2f(w2[i], zv[i], a2);
                    else                   a3 = dot2f(w2[i], zv[i], a3);
                }
                float z = fmaxf(bh1_r + pxor1((a0 + a1) + (a2 + a3)), 0.f);
                if (kh == 0) ((_Float16*)zBu)[c] = (_Float16)z;
            }
            __syncthreads();

            // ---- phase 3: G3 zB -> zA ----
            {
                uint32_t zv[32];
                const uint32_t* zp = zBu + kh * 32;
                #pragma unroll
                for (int q = 0; q < 8; ++q)
                    *(uint4*)&zv[4 * q] = *(const uint4*)(zp + 4 * q);
                float a0 = 0.f, a1 = 0.f, a2 = 0.f, a3 = 0.f;
                #pragma unroll
                for (int i = 0; i < 32; ++i) {
                    if ((i & 3) == 0)      a0 = dot2f(w3[i], zv[i], a0);
                    else if ((i & 3) == 1) a1 = dot2f(w3[i], zv[i], a1);
                    else if ((i & 3) == 2) a2 = dot2f(w3[i], zv[i], a2);
                    else                   a3 = dot2f(w3[i], zv[i], a3);
                }
                float z = fmaxf(bh2_r + pxor1((a0 + a1) + (a2 + a3)), 0.f);
                if (kh == 0) ((_Float16*)zAu)[c] = (_Float16)z;
            }
            __syncthreads();

            // ---- phase 4: G4 (3 A-cols) + in-register einsum + RK4 ----
            {
                uint32_t zv[32];
                const uint32_t* zp = zAu + kh * 32;
                #pragma unroll
                for (int q = 0; q < 8; ++q)
                    *(uint4*)&zv[4 * q] = *(const uint4*)(zp + 4 * q);
                float p0 = 0.f, p1 = 0.f, p2 = 0.f, p3 = 0.f, p4 = 0.f, p5 = 0.f;
                #pragma unroll
                for (int i = 0; i < 16; ++i) {
                    uint32_t ze = zv[2 * i], zo = zv[2 * i + 1];
                    p0 = dot2f(w4[2 * i],          ze, p0);
                    p1 = dot2f(w4[2 * i + 1],      zo, p1);
                    p2 = dot2f(w4[32 + 2 * i],     ze, p2);
                    p3 = dot2f(w4[32 + 2 * i + 1], zo, p3);
                    p4 = dot2f(w4[64 + 2 * i],     ze, p4);
                    p5 = dot2f(w4[64 + 2 * i + 1], zo, p5);
                }
                float av0 = bo[0] + pxor1(p0 + p1);
                float av1 = bo[1] + pxor1(p2 + p3);
                float av2 = bo[2] + pxor1(p4 + p5);
                float kvp = tanh_fast(av0) * dxr[0]
                          + tanh_fast(av1) * dxr[1]
                          + tanh_fast(av2) * dxr[2];
                float kv = pxor2(kvp);          // row-pair (c, c^1) -> full row sum

                hacc += ((s4 == 1 || s4 == 2) ? 2.0f : 1.0f) * kv;
                float hs;
                if (s4 < 3) {
                    hs = h_reg + ((s4 == 2) ? 1.0f : 0.5f) * kv;
                } else {
                    h_reg += hacc * (1.0f / 6.0f);
                    hacc = 0.f;
                    hs = h_reg;
                }
                if (wrt) {
                    ((_Float16*)hinu)[r_own] = (_Float16)hs;
                    if (s4 == 3) hbuf[r_own] = h_reg;
                }
            }
            // dX for step+1 (read at next step's s4==0, after the barrier below)
            if (s4 == 3 && step + 2 < T_ && t < IN_) {
                dxs[t] = xb - xa;
                xa = xb;
                if (step + 3 < T_) xb = x[xbase + (size_t)(step + 3) * IN_ + t];
            }
            __syncthreads();
        }
    }

    OUT_STAGE(T_ - 1)
#undef OUT_STAGE
}

} // namespace

extern "C" void kernel_launch(void* const* d_in, const int* in_sizes, int n_in,
                              void* d_out, int out_size, void* d_ws, size_t ws_size,
                              hipStream_t stream) {
    const float* x      = (const float*)d_in[0];
    const float* W_init = (const float*)d_in[1];
    const float* b_init = (const float*)d_in[2];
    const float* W_in   = (const float*)d_in[3];
    const float* b_in   = (const float*)d_in[4];
    const float* W_h1   = (const float*)d_in[5];
    const float* b_h1   = (const float*)d_in[6];
    const float* W_h2   = (const float*)d_in[7];
    const float* b_h2   = (const float*)d_in[8];
    const float* W_out  = (const float*)d_in[9];
    const float* b_out  = (const float*)d_in[10];
    const float* W_fin  = (const float*)d_in[11];
    const float* b_fin  = (const float*)d_in[12];
    float* out = (float*)d_out;

    cde_kernel<<<dim3(B_), dim3(256), 0, stream>>>(
        x, W_init, b_init, W_in, b_in, W_h1, b_h1, W_h2, b_h2,
        W_out, b_out, W_fin, b_fin, out);
}